// Round 2
// baseline (112.611 us; speedup 1.0000x reference)
//
#include <hip/hip_runtime.h>

// Smoothness loss, 1x3x224x224 f32 inputs, scalar f32 output.
// One window pass per pixel computes er_o, er_s(=sum ti), and BOTH branch
// sums; use_large selects at the end. OOB neighbors load 0 which reproduces
// the reference's zero-padding semantics exactly (incl. the unmasked cd).

#define WSR 10
#define KK  21
#define HH  224
#define WW  224
#define HWSZ (HH*WW)
#define SIG_COLOR 50.0f          // 1/(0.1^2 * 2)
#define SIG_SPACE (1.0f/98.0f)   // 1/(7^2 * 2)
#define LPW 0.8f
#define C1T 10.0f
#define C2T 5.0f
#define ALPHA_W 5.0f
#define EPSV 1e-6f
#define LOG2E 1.44269504088896f

// hardware transcendentals: v_exp_f32 is 2^x, v_log_f32 is log2(x)
__device__ __forceinline__ float fexp2(float x) { return __builtin_amdgcn_exp2f(x); }
__device__ __forceinline__ float flog2(float x) { return __builtin_amdgcn_logf(x); }
__device__ __forceinline__ float fexpe(float x) { return fexp2(x * LOG2E); }

__global__ __launch_bounds__(256) void smooth_loss_main(
    const float* __restrict__ orig, const float* __restrict__ smo,
    float* __restrict__ partials)
{
    __shared__ float w1[KK];
    __shared__ float racc[4][256];

    const int tid = threadIdx.x;
    if (tid < KK) {
        float d = (float)(tid - WSR);
        w1[tid] = fexpe(-SIG_SPACE * d * d);
    }
    __syncthreads();

    const int lane = tid & 63;
    const int wv   = tid >> 6;               // wave id 0..3: splits window rows
    const int pix  = blockIdx.x * 64 + lane; // 784 blocks * 64 = 50176 exactly
    const int py   = pix / WW;
    const int px   = pix - py * WW;

    const float oc0 = orig[pix], oc1 = orig[pix + HWSZ], oc2 = orig[pix + 2*HWSZ];
    const float sc0 = smo[pix],  sc1 = smo[pix + HWSZ],  sc2 = smo[pix + 2*HWSZ];

    // wave 0: rows 0..5 (6 rows); waves 1..3: 5 rows each
    const int ky0 = (wv == 0) ? 0 : (5 * wv + 1);
    const int kyn = (wv == 0) ? 6 : 5;

    float er_o = 0.f, er_s = 0.f, sl = 0.f, ss = 0.f;

    for (int kyi = 0; kyi < kyn; ++kyi) {
        const int ky = ky0 + kyi;
        const int y  = py + ky - WSR;
        const bool yv = ((unsigned)y < (unsigned)HH);
        const float wy = w1[ky];
        const int rb = y * WW;
        #pragma unroll 7
        for (int kx = 0; kx < KK; ++kx) {
            const int x = px + kx - WSR;
            const bool v = yv & ((unsigned)x < (unsigned)WW);
            const int ni = rb + x;
            float o0 = 0.f, o1 = 0.f, o2 = 0.f;
            float s0 = 0.f, s1 = 0.f, s2 = 0.f;
            if (v) {
                o0 = orig[ni]; o1 = orig[ni + HWSZ]; o2 = orig[ni + 2*HWSZ];
                s0 = smo[ni];  s1 = smo[ni + HWSZ];  s2 = smo[ni + 2*HWSZ];
            }
            // edge response of original (masked diff, p > 0)
            float d0 = (o0 > 0.f) ? (o0 - oc0) : 0.f;
            float d1 = (o1 > 0.f) ? (o1 - oc1) : 0.f;
            float d2 = (o2 > 0.f) ? (o2 - oc2) : 0.f;
            er_o += fabsf(d0) + fabsf(d1) + fabsf(d2);
            // ti = |masked smooth diff|; er_s is exactly sum(ti)
            float t0 = (s0 > 0.f) ? fabsf(s0 - sc0) : 0.f;
            float t1 = (s1 > 0.f) ? fabsf(s1 - sc1) : 0.f;
            float t2 = (s2 > 0.f) ? fabsf(s2 - sc2) : 0.f;
            er_s += t0 + t1 + t2;
            // color affinity from original, UNMASKED diff (faithful quirk):
            float e0 = o0 - oc0, e1 = o1 - oc1, e2 = o2 - oc2;
            float wr = fexpe(-SIG_COLOR * (e0*e0 + e1*e1 + e2*e2));
            // spatial affinity, separable gaussian
            float wsp = wy * w1[kx];
            sl += wsp * (t0*t0 + t1*t1 + t2*t2);
            // (ti + eps)^0.8 via exp2(0.8*log2)
            float p0 = fexp2(LPW * flog2(t0 + EPSV));
            float p1 = fexp2(LPW * flog2(t1 + EPSV));
            float p2 = fexp2(LPW * flog2(t2 + EPSV));
            ss += wr * (p0 + p1 + p2);
        }
    }

    racc[0][tid] = er_o; racc[1][tid] = er_s;
    racc[2][tid] = sl;   racc[3][tid] = ss;
    __syncthreads();

    if (wv == 0) {
        float eo = racc[0][lane] + racc[0][64+lane] + racc[0][128+lane] + racc[0][192+lane];
        float es = racc[1][lane] + racc[1][64+lane] + racc[1][128+lane] + racc[1][192+lane];
        float l  = racc[2][lane] + racc[2][64+lane] + racc[2][128+lane] + racc[2][192+lane];
        float s  = racc[3][lane] + racc[3][64+lane] + racc[3][128+lane] + racc[3][192+lane];
        const bool use_large = (eo < C1T) && ((es - eo) > C2T);
        float contrib = use_large ? (ALPHA_W * l) : s;
        #pragma unroll
        for (int off = 32; off > 0; off >>= 1)
            contrib += __shfl_down(contrib, off, 64);
        if (lane == 0) partials[blockIdx.x] = contrib;
    }
}

__global__ __launch_bounds__(256) void smooth_loss_reduce(
    const float* __restrict__ partials, float* __restrict__ out, int n)
{
    __shared__ float red[256];
    const int tid = threadIdx.x;
    float v = 0.f;
    for (int i = tid; i < n; i += 256) v += partials[i];
    red[tid] = v;
    __syncthreads();
    if (tid < 128) red[tid] += red[tid + 128];
    __syncthreads();
    if (tid < 64) {
        float x = red[tid] + red[tid + 64];
        #pragma unroll
        for (int off = 32; off > 0; off >>= 1)
            x += __shfl_down(x, off, 64);
        if (tid == 0)
            out[0] = x * (1.0f / ((float)HWSZ * (float)(WSR * WSR)));
    }
}

extern "C" void kernel_launch(void* const* d_in, const int* in_sizes, int n_in,
                              void* d_out, int out_size, void* d_ws, size_t ws_size,
                              hipStream_t stream) {
    const float* orig = (const float*)d_in[0];   // original_images
    const float* smo  = (const float*)d_in[1];   // smooth_images
    float* out = (float*)d_out;
    float* partials = (float*)d_ws;              // 784 floats of scratch

    const int nblocks = (HWSZ / 64);             // 784
    smooth_loss_main<<<nblocks, 256, 0, stream>>>(orig, smo, partials);
    smooth_loss_reduce<<<1, 256, 0, stream>>>(partials, out, nblocks);
}